// Round 1
// baseline (1068.632 us; speedup 1.0000x reference)
//
#include <hip/hip_runtime.h>
#include <stdint.h>

// Problem constants
#define B_    256
#define T_    512
#define DIN   512
#define H_    512
#define NEMB_ 96
#define BT    131072   // B_*T_

typedef __attribute__((ext_vector_type(8))) short short8;   // 8 bf16 (4 VGPRs)
typedef __attribute__((ext_vector_type(4))) float f32x4;

__device__ __forceinline__ unsigned bf16_rne(float f) {
    unsigned u = __float_as_uint(f);
    return (u + 0x7FFF + ((u >> 16) & 1)) >> 16;
}
__device__ __forceinline__ unsigned pack2(float a, float b) {
    return bf16_rne(a) | (bf16_rne(b) << 16);
}
__device__ __forceinline__ float tanh_fast(float x) {
    // 1 - 2/(1+e^{2x}); self-saturating at +-1 for large |x|
    float ex = __expf(2.f * x);
    return 1.f - 2.f / (ex + 1.f);
}
__device__ __forceinline__ float sigmoid_fast(float x) {
    return 1.f / (1.f + __expf(-x));
}

// ---------------- kernel 0: Wi2h fp32 -> bf16 ----------------
__global__ void k_cvt(const float* __restrict__ W, unsigned* __restrict__ Wb) {
    int i = blockIdx.x * 256 + threadIdx.x;          // 131072 uints (2 bf16 each)
    float2 f = ((const float2*)W)[i];
    Wb[i] = pack2(f.x, f.y);
}

// ---------------- kernel 1: prevproj = h @ Wh2h^T + bh2h ----------------
__global__ void k_prevproj(const float* __restrict__ hin, const float* __restrict__ Whh,
                           const float* __restrict__ bh, float* __restrict__ pp) {
    __shared__ float hs[512];
    int b = blockIdx.x;
    int t = threadIdx.x;                              // 512 threads, one output each
    hs[t] = hin[b * 512 + t];
    __syncthreads();
    const float4* wr = (const float4*)(Whh + (size_t)t * 512);
    const float4* hv = (const float4*)hs;
    float acc = 0.f;
#pragma unroll 8
    for (int k = 0; k < 128; ++k) {
        float4 w = wr[k], x = hv[k];
        acc += w.x * x.x + w.y * x.y + w.z * x.z + w.w * x.w;
    }
    pp[b * 512 + t] = acc + bh[t];
}

// ---------------- kernel 2: attention scores (the big GEMM, fused tanh+dot) ----
// e[b,t] = sum_h Wscore[h] * tanh( sum_d batch_H[b,t,d]*Wi2h[h,d] + pp[b,h] )
// BM=64 rows/block (4 waves x 16), full H in-block (32 n-tiles), K=512 (16 chunks).
// LDS holds the A tile (64x512 bf16 = exactly 64KB) pre-arranged in MFMA A-frag
// slot order: uint4 slot index = wave*1024 + kchunk*64 + lane  -> conflict-free
// ds_read_b128 in the K loop (write-side conflicts only touch 1/33 of traffic).
__launch_bounds__(256, 2)
__global__ void k_scores(const float* __restrict__ A,              // batch_H [BT,512]
                         const unsigned short* __restrict__ Wb,    // bf16 Wi2h [512,512]
                         const float* __restrict__ pp,             // [B_,512]
                         const float* __restrict__ wsc,            // Wscore [512]
                         float* __restrict__ e)                    // [BT]
{
    __shared__ uint4 ldsA[4096];                                   // 65536 B
    int tid = threadIdx.x;
    int blockRow = blockIdx.x * 64;
    int b = blockRow >> 9;                                         // 8 blocks per batch row

    // ---- stage A tile 64x512 fp32 -> bf16 into fragment-order slots ----
    const float4* A4 = (const float4*)A;
#pragma unroll
    for (int it = 0; it < 16; ++it) {
        int i = it * 256 + tid;          // 0..4095
        int row = i >> 6;                // 0..63
        int j = i & 63;                  // 8-float group along K
        size_t gidx = (size_t)(blockRow + row) * 128 + (size_t)j * 2;
        float4 f0 = A4[gidx], f1 = A4[gidx + 1];
        uint4 u;
        u.x = pack2(f0.x, f0.y); u.y = pack2(f0.z, f0.w);
        u.z = pack2(f1.x, f1.y); u.w = pack2(f1.z, f1.w);
        // slot: wave(row>>4)*1024 + kchunk(j>>2)*64 + lane((j&3)*16 + (row&15))
        int li = ((row >> 4) << 10) + ((j >> 2) << 6) + ((j & 3) << 4) + (row & 15);
        ldsA[li] = u;
    }
    __syncthreads();

    int wave = tid >> 6, lane = tid & 63;
    int m = lane & 15, q = lane >> 4;
    const short8* aP = (const short8*)ldsA + wave * 1024 + lane;   // 16B units

    float eacc0 = 0.f, eacc1 = 0.f, eacc2 = 0.f, eacc3 = 0.f;
    for (int n0 = 0; n0 < 512; n0 += 16) {
        float ppv = pp[b * 512 + n0 + m];        // indexed by col = lane&15
        float wsv = wsc[n0 + m];
        f32x4 acc = {0.f, 0.f, 0.f, 0.f};
        const short8* bP = (const short8*)(Wb + (size_t)(n0 + m) * 512 + q * 8);
#pragma unroll
        for (int c = 0; c < 16; ++c) {
            short8 av = aP[c * 64];              // A[m][c*32 + q*8 ..+7]
            short8 bv = bP[c * 4];               // Wi2h[n0+m][c*32 + q*8 ..+7]
            acc = __builtin_amdgcn_mfma_f32_16x16x32_bf16(av, bv, acc, 0, 0, 0);
        }
        // C/D layout: col = lane&15, row = q*4 + r  (verified m89/m91)
#pragma unroll
        for (int r = 0; r < 4; ++r) {
            float v = tanh_fast(acc[r] + ppv) * wsv;
            if      (r == 0) eacc0 += v;
            else if (r == 1) eacc1 += v;
            else if (r == 2) eacc2 += v;
            else             eacc3 += v;
        }
    }
    // reduce over the 16 columns (lanes sharing same q group)
#pragma unroll
    for (int off = 1; off < 16; off <<= 1) {
        eacc0 += __shfl_xor(eacc0, off, 16);
        eacc1 += __shfl_xor(eacc1, off, 16);
        eacc2 += __shfl_xor(eacc2, off, 16);
        eacc3 += __shfl_xor(eacc3, off, 16);
    }
    if (m == 0) {
        int rb = blockRow + wave * 16 + q * 4;
        e[rb + 0] = eacc0; e[rb + 1] = eacc1; e[rb + 2] = eacc2; e[rb + 3] = eacc3;
    }
}

// ---------------- kernel 3: softmax over T (in-place on alpha buffer) --------
__global__ void k_softmax(float* __restrict__ ealpha) {
    __shared__ float red[8];
    int b = blockIdx.x, tid = threadIdx.x;           // 256 threads, 2 elems each
    float v0 = ealpha[b * 512 + tid];
    float v1 = ealpha[b * 512 + 256 + tid];
    float mx = fmaxf(v0, v1);
    for (int off = 32; off; off >>= 1) mx = fmaxf(mx, __shfl_xor(mx, off, 64));
    if ((tid & 63) == 0) red[tid >> 6] = mx;
    __syncthreads();
    mx = fmaxf(fmaxf(red[0], red[1]), fmaxf(red[2], red[3]));
    float x0 = __expf(v0 - mx), x1 = __expf(v1 - mx);
    float s = x0 + x1;
    for (int off = 32; off; off >>= 1) s += __shfl_xor(s, off, 64);
    if ((tid & 63) == 0) red[4 + (tid >> 6)] = s;
    __syncthreads();
    s = red[4] + red[5] + red[6] + red[7];
    float inv = 1.f / s;
    ealpha[b * 512 + tid]       = x0 * inv;
    ealpha[b * 512 + 256 + tid] = x1 * inv;
}

// ---------------- kernel 4: context = alpha^T batch_H ------------------------
__global__ void k_context(const float* __restrict__ A, const float* __restrict__ alpha,
                          float* __restrict__ ctx) {
    int b = blockIdx.x >> 3, chunk = blockIdx.x & 7;
    int tid = threadIdx.x;                            // 256 threads, 2 floats each
    const float2* A2 = (const float2*)A;
    float ax = 0.f, ay = 0.f;
    int t0 = chunk * 64;
    for (int t = 0; t < 64; ++t) {
        float a = alpha[b * 512 + t0 + t];            // uniform -> scalar load
        float2 v = A2[(size_t)(b * 512 + t0 + t) * 256 + tid];
        ax += a * v.x; ay += a * v.y;
    }
    atomicAdd(&ctx[b * 512 + tid * 2],     ax);
    atomicAdd(&ctx[b * 512 + tid * 2 + 1], ay);
}

// ---------------- kernel 5: gates = x@W_ih^T + h@W_hh^T + biases -------------
// virtual K=1120: x = [context(512) | onehot(96) | h(512)], B = [W_ih | W_hh]
__launch_bounds__(256)
__global__ void k_gates(const float* __restrict__ ctx, const float* __restrict__ oneh,
                        const float* __restrict__ hin,
                        const float* __restrict__ Wih, const float* __restrict__ Whh,
                        const float* __restrict__ bih, const float* __restrict__ bhh,
                        float* __restrict__ gates) {
    __shared__ float As[32][33];
    __shared__ float Bs[32][64];
    int bT = blockIdx.x;                              // 0..7  (batch tiles of 32)
    int gT = blockIdx.y;                              // 0..31 (gate tiles of 64)
    int tid = threadIdx.x;
    int col = tid & 63;                               // g within tile
    int rg = tid >> 6;                                // row group: rows rg*8..+7
    float acc[8] = {0, 0, 0, 0, 0, 0, 0, 0};
    for (int k0 = 0; k0 < 1120; k0 += 32) {
        for (int i = tid; i < 1024; i += 256) {       // A tile 32x32
            int r = i >> 5, kk = i & 31;
            int bb = bT * 32 + r, k = k0 + kk;
            float v;
            if (k < 512)      v = ctx[bb * 512 + k];
            else if (k < 608) v = oneh[bb * 96 + (k - 512)];
            else              v = hin[bb * 512 + (k - 608)];
            As[r][kk] = v;
        }
        for (int i = tid; i < 2048; i += 256) {       // B tile 32k x 64g
            int kk = i >> 6, cc = i & 63;
            int g = gT * 64 + cc, k = k0 + kk;
            float v;
            if (k < 608) v = Wih[(size_t)g * 608 + k];
            else         v = Whh[(size_t)g * 512 + (k - 608)];
            Bs[kk][cc] = v;
        }
        __syncthreads();
#pragma unroll 8
        for (int kk = 0; kk < 32; ++kk) {
            float bv = Bs[kk][col];
#pragma unroll
            for (int r = 0; r < 8; ++r)
                acc[r] += As[rg * 8 + r][kk] * bv;
        }
        __syncthreads();
    }
    int g = gT * 64 + col;
    float bias = bih[g] + bhh[g];
#pragma unroll
    for (int r = 0; r < 8; ++r) {
        int bb = bT * 32 + rg * 8 + r;
        gates[(size_t)bb * 2048 + g] = acc[r] + bias;
    }
}

// ---------------- kernel 6: LSTM pointwise -----------------------------------
__global__ void k_lstm(const float* __restrict__ gates, const float* __restrict__ c,
                       float* __restrict__ out) {
    int i = blockIdx.x * 256 + threadIdx.x;           // 131072
    int b = i >> 9, u = i & 511;
    const float* g = gates + (size_t)b * 2048;
    float si = sigmoid_fast(g[u]);
    float sf = sigmoid_fast(g[512 + u]);
    float tg = tanh_fast(g[1024 + u]);
    float so = sigmoid_fast(g[1536 + u]);
    float cn = sf * c[i] + si * tg;
    float hn = so * tanh_fast(cn);
    out[i] = hn;                                      // h_new
    out[BT + i] = cn;                                 // c_new
}

extern "C" void kernel_launch(void* const* d_in, const int* in_sizes, int n_in,
                              void* d_out, int out_size, void* d_ws, size_t ws_size,
                              hipStream_t stream) {
    const float* hin  = (const float*)d_in[0];
    const float* c    = (const float*)d_in[1];
    const float* bH   = (const float*)d_in[2];
    const float* oneh = (const float*)d_in[3];
    const float* Wi2h = (const float*)d_in[4];
    const float* Wh2h = (const float*)d_in[5];
    const float* bh2h = (const float*)d_in[6];
    const float* Wsc  = (const float*)d_in[7];
    const float* Wih  = (const float*)d_in[8];
    const float* Whh  = (const float*)d_in[9];
    const float* bih  = (const float*)d_in[10];
    const float* bhh  = (const float*)d_in[11];
    float* out = (float*)d_out;
    float* alpha = out + 2 * BT;                      // output slot 3; also holds e

    char* w = (char*)d_ws;                            // needs 3.67 MB of ws
    unsigned* Wb  = (unsigned*)w;                     // bf16 Wi2h, 512 KB
    float* pp     = (float*)(w + 524288);             // [B_,512]
    float* ctx    = (float*)(w + 1048576);            // [B_,512]
    float* gates  = (float*)(w + 1572864);            // [B_,2048], 2 MB

    hipMemsetAsync(ctx, 0, 524288, stream);           // context accumulated via atomics
    k_cvt     <<<512, 256, 0, stream>>>(Wi2h, Wb);
    k_prevproj<<<256, 512, 0, stream>>>(hin, Wh2h, bh2h, pp);
    k_scores  <<<2048, 256, 0, stream>>>(bH, (const unsigned short*)Wb, pp, Wsc, alpha);
    k_softmax <<<256, 256, 0, stream>>>(alpha);
    k_context <<<2048, 256, 0, stream>>>(bH, alpha, ctx);
    k_gates   <<<dim3(8, 32), 256, 0, stream>>>(ctx, oneh, hin, Wih, Whh, bih, bhh, gates);
    k_lstm    <<<512, 256, 0, stream>>>(gates, c, out);
}

// Round 2
// 786.195 us; speedup vs baseline: 1.3592x; 1.3592x over previous
//
#include <hip/hip_runtime.h>
#include <stdint.h>

// Problem constants
#define B_    256
#define T_    512
#define DIN   512
#define H_    512
#define NEMB_ 96
#define BT    131072   // B_*T_

typedef __attribute__((ext_vector_type(8))) short short8;    // 8 bf16 (4 VGPRs)
typedef __attribute__((ext_vector_type(4))) float f32x4;
typedef __attribute__((ext_vector_type(16))) float f32x16;

__device__ __forceinline__ unsigned bf16_rne(float f) {
    unsigned u = __float_as_uint(f);
    return (u + 0x7FFF + ((u >> 16) & 1)) >> 16;
}
__device__ __forceinline__ unsigned pack2(float a, float b) {
    return bf16_rne(a) | (bf16_rne(b) << 16);
}
__device__ __forceinline__ float tanh_fast(float x) {
    float ex = __expf(2.f * x);
    return 1.f - 2.f / (ex + 1.f);
}
__device__ __forceinline__ float sigmoid_fast(float x) {
    return 1.f / (1.f + __expf(-x));
}

// ---------------- kernel 0: Wi2h fp32 -> bf16 ----------------
__global__ void k_cvt(const float* __restrict__ W, unsigned* __restrict__ Wb) {
    int i = blockIdx.x * 256 + threadIdx.x;          // 131072 uints (2 bf16 each)
    float2 f = ((const float2*)W)[i];
    Wb[i] = pack2(f.x, f.y);
}

// ---------------- kernel 1: prevproj = h @ Wh2h^T + bh2h ----------------
__global__ void k_prevproj(const float* __restrict__ hin, const float* __restrict__ Whh,
                           const float* __restrict__ bh, float* __restrict__ pp) {
    __shared__ float hs[512];
    int b = blockIdx.x;
    int t = threadIdx.x;                              // 512 threads, one output each
    hs[t] = hin[b * 512 + t];
    __syncthreads();
    const float4* wr = (const float4*)(Whh + (size_t)t * 512);
    const float4* hv = (const float4*)hs;
    float acc = 0.f;
#pragma unroll 8
    for (int k = 0; k < 128; ++k) {
        float4 w = wr[k], x = hv[k];
        acc += w.x * x.x + w.y * x.y + w.z * x.z + w.w * x.w;
    }
    pp[b * 512 + t] = acc + bh[t];
}

// ---------------- kernel 2: attention scores (fused GEMM+tanh+dot) -----------
// e[b,t] = sum_h Wscore[h] * tanh( sum_d batch_H[b,t,d]*Wi2h[h,d] + pp[b,h] )
// BM=64 rows/block. 32x32x16 MFMA, 2x2 register tile per wave (64 rows x 64
// cols), waves split the 512 H-columns 4 ways (block reads Wb exactly once).
// A tile 64x512 bf16 = 64KB LDS with XOR-swizzled 16B slots:
//   slot(row, g) = row*64 + (g ^ (row&7)),  g = k/8  (0..63)
// -> conflict-free ds_write_b128 (staging: lane=g, coalesced global) and
//    conflict-free ds_read_b128 (K loop: lanes 0..31 = rows).
__launch_bounds__(256, 2)
__global__ void k_scores(const float* __restrict__ A,              // batch_H [BT,512]
                         const unsigned short* __restrict__ Wb,    // bf16 Wi2h [512,512]
                         const float* __restrict__ pp,             // [B_,512]
                         const float* __restrict__ wsc,            // Wscore [512]
                         float* __restrict__ e)                    // [BT]
{
    __shared__ uint4 ldsA[4096];                                   // 65536 B
    __shared__ float es[64];
    int tid = threadIdx.x;
    int blockRow = blockIdx.x * 64;
    int b = blockRow >> 9;                                         // 8 blocks per batch row
    int lane = tid & 63, wave = tid >> 6;
    int l31 = lane & 31, lh = lane >> 5, l7 = lane & 7;

    if (tid < 64) es[tid] = 0.f;

    // ---- stage A tile 64x512 fp32 -> bf16, coalesced reads, swizzled writes ----
    const float4* A4 = (const float4*)A;
#pragma unroll
    for (int it = 0; it < 16; ++it) {
        int row = it * 4 + wave;                      // one row per wave-iteration
        size_t gidx = (size_t)(blockRow + row) * 128 + (size_t)lane * 2;
        float4 f0 = A4[gidx], f1 = A4[gidx + 1];
        uint4 u;
        u.x = pack2(f0.x, f0.y); u.y = pack2(f0.z, f0.w);
        u.z = pack2(f1.x, f1.y); u.w = pack2(f1.z, f1.w);
        ldsA[row * 64 + (lane ^ (row & 7))] = u;
    }
    __syncthreads();

    const short8* lds8 = (const short8*)ldsA;
    int base0 = l31 * 64;                             // rtile 0: rows 0..31
    int base1 = (32 + l31) * 64;                      // rtile 1: rows 32..63

    float eacc[32];
#pragma unroll
    for (int i = 0; i < 32; ++i) eacc[i] = 0.f;

#pragma unroll
    for (int ni = 0; ni < 2; ++ni) {
        int n0 = wave * 128 + ni * 64 + l31;          // this lane's col (ctile 0)
        const short8* b0p = (const short8*)(Wb + (size_t)n0 * 512);
        const short8* b1p = (const short8*)(Wb + (size_t)(n0 + 32) * 512);
        f32x16 acc00 = {0.f}, acc01 = {0.f}, acc10 = {0.f}, acc11 = {0.f};
#pragma unroll
        for (int c = 0; c < 32; ++c) {                // K chunks of 16
            int g = c * 2 + lh;                       // k-group of 8 for this lane
            int gx = g ^ l7;
            short8 a0 = lds8[base0 + gx];
            short8 a1 = lds8[base1 + gx];
            short8 b0 = b0p[g];
            short8 b1 = b1p[g];
            acc00 = __builtin_amdgcn_mfma_f32_32x32x16_bf16(a0, b0, acc00, 0, 0, 0);
            acc01 = __builtin_amdgcn_mfma_f32_32x32x16_bf16(a0, b1, acc01, 0, 0, 0);
            acc10 = __builtin_amdgcn_mfma_f32_32x32x16_bf16(a1, b0, acc10, 0, 0, 0);
            acc11 = __builtin_amdgcn_mfma_f32_32x32x16_bf16(a1, b1, acc11, 0, 0, 0);
        }
        // epilogue: tanh + Wscore dot, accumulate per (rtile, reg)
        float pp0 = pp[b * 512 + n0],      ws0 = wsc[n0];
        float pp1 = pp[b * 512 + n0 + 32], ws1 = wsc[n0 + 32];
#pragma unroll
        for (int r = 0; r < 16; ++r) {
            eacc[r]      += tanh_fast(acc00[r] + pp0) * ws0
                          + tanh_fast(acc01[r] + pp1) * ws1;
            eacc[16 + r] += tanh_fast(acc10[r] + pp0) * ws0
                          + tanh_fast(acc11[r] + pp1) * ws1;
        }
    }

    // reduce over the 32 cols held by lanes 0..31 / 32..63 (rows differ by lh*4)
#pragma unroll
    for (int i = 0; i < 32; ++i) {
#pragma unroll
        for (int off = 1; off < 32; off <<= 1)
            eacc[i] += __shfl_xor(eacc[i], off, 64);
    }
    if (l31 == 0) {
#pragma unroll
        for (int rt = 0; rt < 2; ++rt)
#pragma unroll
            for (int r = 0; r < 16; ++r) {
                int row = rt * 32 + lh * 4 + (r & 3) + 8 * (r >> 2);
                atomicAdd(&es[row], eacc[rt * 16 + r]);
            }
    }
    __syncthreads();
    if (tid < 64) e[blockRow + tid] = es[tid];
}

// ---------------- kernel 3: softmax over T (in-place on alpha buffer) --------
__global__ void k_softmax(float* __restrict__ ealpha) {
    __shared__ float red[8];
    int b = blockIdx.x, tid = threadIdx.x;           // 256 threads, 2 elems each
    float v0 = ealpha[b * 512 + tid];
    float v1 = ealpha[b * 512 + 256 + tid];
    float mx = fmaxf(v0, v1);
    for (int off = 32; off; off >>= 1) mx = fmaxf(mx, __shfl_xor(mx, off, 64));
    if ((tid & 63) == 0) red[tid >> 6] = mx;
    __syncthreads();
    mx = fmaxf(fmaxf(red[0], red[1]), fmaxf(red[2], red[3]));
    float x0 = __expf(v0 - mx), x1 = __expf(v1 - mx);
    float s = x0 + x1;
    for (int off = 32; off; off >>= 1) s += __shfl_xor(s, off, 64);
    if ((tid & 63) == 0) red[4 + (tid >> 6)] = s;
    __syncthreads();
    s = red[4] + red[5] + red[6] + red[7];
    float inv = 1.f / s;
    ealpha[b * 512 + tid]       = x0 * inv;
    ealpha[b * 512 + 256 + tid] = x1 * inv;
}

// ---------------- kernel 4: context = alpha^T batch_H ------------------------
__global__ void k_context(const float* __restrict__ A, const float* __restrict__ alpha,
                          float* __restrict__ ctx) {
    int b = blockIdx.x >> 3, chunk = blockIdx.x & 7;
    int tid = threadIdx.x;                            // 256 threads, 2 floats each
    const float2* A2 = (const float2*)A;
    float ax = 0.f, ay = 0.f;
    int t0 = chunk * 64;
    for (int t = 0; t < 64; ++t) {
        float a = alpha[b * 512 + t0 + t];            // uniform -> scalar load
        float2 v = A2[(size_t)(b * 512 + t0 + t) * 256 + tid];
        ax += a * v.x; ay += a * v.y;
    }
    atomicAdd(&ctx[b * 512 + tid * 2],     ax);
    atomicAdd(&ctx[b * 512 + tid * 2 + 1], ay);
}

// ---------------- kernel 5: gates = x@W_ih^T + h@W_hh^T + biases -------------
// virtual K=1120: x = [context(512) | onehot(96) | h(512)], B = [W_ih | W_hh]
__launch_bounds__(256)
__global__ void k_gates(const float* __restrict__ ctx, const float* __restrict__ oneh,
                        const float* __restrict__ hin,
                        const float* __restrict__ Wih, const float* __restrict__ Whh,
                        const float* __restrict__ bih, const float* __restrict__ bhh,
                        float* __restrict__ gates) {
    __shared__ float As[32][33];
    __shared__ float Bs[32][64];
    int bT = blockIdx.x;                              // 0..7  (batch tiles of 32)
    int gT = blockIdx.y;                              // 0..31 (gate tiles of 64)
    int tid = threadIdx.x;
    int col = tid & 63;                               // g within tile
    int rg = tid >> 6;                                // row group: rows rg*8..+7
    float acc[8] = {0, 0, 0, 0, 0, 0, 0, 0};
    for (int k0 = 0; k0 < 1120; k0 += 32) {
        for (int i = tid; i < 1024; i += 256) {       // A tile 32x32
            int r = i >> 5, kk = i & 31;
            int bb = bT * 32 + r, k = k0 + kk;
            float v;
            if (k < 512)      v = ctx[bb * 512 + k];
            else if (k < 608) v = oneh[bb * 96 + (k - 512)];
            else              v = hin[bb * 512 + (k - 608)];
            As[r][kk] = v;
        }
        for (int i = tid; i < 2048; i += 256) {       // B tile 32k x 64g
            int kk = i >> 6, cc = i & 63;
            int g = gT * 64 + cc, k = k0 + kk;
            float v;
            if (k < 608) v = Wih[(size_t)g * 608 + k];
            else         v = Whh[(size_t)g * 512 + (k - 608)];
            Bs[kk][cc] = v;
        }
        __syncthreads();
#pragma unroll 8
        for (int kk = 0; kk < 32; ++kk) {
            float bv = Bs[kk][col];
#pragma unroll
            for (int r = 0; r < 8; ++r)
                acc[r] += As[rg * 8 + r][kk] * bv;
        }
        __syncthreads();
    }
    int g = gT * 64 + col;
    float bias = bih[g] + bhh[g];
#pragma unroll
    for (int r = 0; r < 8; ++r) {
        int bb = bT * 32 + rg * 8 + r;
        gates[(size_t)bb * 2048 + g] = acc[r] + bias;
    }
}

// ---------------- kernel 6: LSTM pointwise -----------------------------------
__global__ void k_lstm(const float* __restrict__ gates, const float* __restrict__ c,
                       float* __restrict__ out) {
    int i = blockIdx.x * 256 + threadIdx.x;           // 131072
    int b = i >> 9, u = i & 511;
    const float* g = gates + (size_t)b * 2048;
    float si = sigmoid_fast(g[u]);
    float sf = sigmoid_fast(g[512 + u]);
    float tg = tanh_fast(g[1024 + u]);
    float so = sigmoid_fast(g[1536 + u]);
    float cn = sf * c[i] + si * tg;
    float hn = so * tanh_fast(cn);
    out[i] = hn;                                      // h_new
    out[BT + i] = cn;                                 // c_new
}

extern "C" void kernel_launch(void* const* d_in, const int* in_sizes, int n_in,
                              void* d_out, int out_size, void* d_ws, size_t ws_size,
                              hipStream_t stream) {
    const float* hin  = (const float*)d_in[0];
    const float* c    = (const float*)d_in[1];
    const float* bH   = (const float*)d_in[2];
    const float* oneh = (const float*)d_in[3];
    const float* Wi2h = (const float*)d_in[4];
    const float* Wh2h = (const float*)d_in[5];
    const float* bh2h = (const float*)d_in[6];
    const float* Wsc  = (const float*)d_in[7];
    const float* Wih  = (const float*)d_in[8];
    const float* Whh  = (const float*)d_in[9];
    const float* bih  = (const float*)d_in[10];
    const float* bhh  = (const float*)d_in[11];
    float* out = (float*)d_out;
    float* alpha = out + 2 * BT;                      // output slot 3; also holds e

    char* w = (char*)d_ws;                            // needs 3.67 MB of ws
    unsigned* Wb  = (unsigned*)w;                     // bf16 Wi2h, 512 KB
    float* pp     = (float*)(w + 524288);             // [B_,512]
    float* ctx    = (float*)(w + 1048576);            // [B_,512]
    float* gates  = (float*)(w + 1572864);            // [B_,2048], 2 MB

    hipMemsetAsync(ctx, 0, 524288, stream);           // context accumulated via atomics
    k_cvt     <<<512, 256, 0, stream>>>(Wi2h, Wb);
    k_prevproj<<<256, 512, 0, stream>>>(hin, Wh2h, bh2h, pp);
    k_scores  <<<2048, 256, 0, stream>>>(bH, (const unsigned short*)Wb, pp, Wsc, alpha);
    k_softmax <<<256, 256, 0, stream>>>(alpha);
    k_context <<<2048, 256, 0, stream>>>(bH, alpha, ctx);
    k_gates   <<<dim3(8, 32), 256, 0, stream>>>(ctx, oneh, hin, Wih, Whh, bih, bhh, gates);
    k_lstm    <<<512, 256, 0, stream>>>(gates, c, out);
}